// Round 1
// baseline (2580.330 us; speedup 1.0000x reference)
//
#include <hip/hip_runtime.h>
#include <hip/hip_bf16.h>

// Problem constants
#define NB 8
#define NL 2500
#define ND 512
#define NY 8921

// Tiling
#define YTL 64            // labels per block
#define MR  128           // G rows per block (2*YTL, U/W interleaved)
#define BN  64            // l-tile
#define BK  64            // k-tile
#define LPAD 2560         // 40 * 64
#define NLT  40           // LPAD/BN
#define NKK  8            // ND/BK
#define NSTEP 320         // NLT*NKK
#define NYB 140           // ceil(NY/YTL)
#define RPAD 17920        // NYB*MR  (Y padded to 8960)

#define GB_BYTES ((size_t)RPAD * ND * 2)        // 18,350,080
#define XB_BYTES ((size_t)NB * LPAD * ND * 2)   // 20,971,520

typedef short s8v __attribute__((ext_vector_type(8)));
typedef float f4v __attribute__((ext_vector_type(4)));

__device__ __forceinline__ unsigned short f2bf(float f) {
  unsigned int u = __float_as_uint(f);
  return (unsigned short)((u + 0x7FFFu + ((u >> 16) & 1u)) >> 16);
}
__device__ __forceinline__ unsigned int pk2(float a, float b) {
  return (unsigned int)f2bf(a) | ((unsigned int)f2bf(b) << 16);
}

// ---- conversion: build interleaved G (row 2y = U[y], 2y+1 = W[y]), zero-padded
__global__ void cvt_g_kernel(const float* __restrict__ U, const float* __restrict__ W,
                             unsigned short* __restrict__ G) {
  size_t c  = (size_t)blockIdx.x * 256 + threadIdx.x;  // chunk of 8 elems
  size_t e0 = c * 8;
  int r = (int)(e0 >> 9);          // row (0..RPAD)
  int k = (int)(e0 & 511);
  int y = r >> 1;
  uint4 o;
  if (y < NY) {
    const float* src = (r & 1) ? W : U;
    const float4* p = (const float4*)(src + (size_t)y * ND + k);
    float4 f0 = p[0], f1 = p[1];
    o.x = pk2(f0.x, f0.y); o.y = pk2(f0.z, f0.w);
    o.z = pk2(f1.x, f1.y); o.w = pk2(f1.z, f1.w);
  } else {
    o = make_uint4(0u, 0u, 0u, 0u);
  }
  *(uint4*)(G + e0) = o;
}

// ---- conversion: x -> bf16, l padded to LPAD with zeros
__global__ void cvt_x_kernel(const float* __restrict__ x, unsigned short* __restrict__ xb) {
  size_t c  = (size_t)blockIdx.x * 256 + threadIdx.x;
  size_t e0 = c * 8;
  int k   = (int)(e0 & 511);
  int row = (int)(e0 >> 9);        // b*LPAD + lp
  int lp  = row % LPAD;
  int b   = row / LPAD;
  uint4 o;
  if (lp < NL) {
    const float4* p = (const float4*)(x + ((size_t)b * NL + lp) * ND + k);
    float4 f0 = p[0], f1 = p[1];
    o.x = pk2(f0.x, f0.y); o.y = pk2(f0.z, f0.w);
    o.z = pk2(f1.x, f1.y); o.w = pk2(f1.z, f1.w);
  } else {
    o = make_uint4(0u, 0u, 0u, 0u);
  }
  *(uint4*)(xb + e0) = o;
}

// ---- fused: dual-GEMM + online softmax + weighted reduce
template<bool PRE>
__global__ __launch_bounds__(256) void fused_kernel(
    const float* __restrict__ xf, const float* __restrict__ Uf,
    const float* __restrict__ Wf, const float* __restrict__ bias,
    const unsigned short* __restrict__ Gb, const unsigned short* __restrict__ xb,
    float* __restrict__ out)
{
  __shared__ uint4 AsRaw[2][1024];   // 2 x 16 KB  (128 rows x 64 bf16, swizzled)
  __shared__ uint4 BsRaw[2][512];    // 2 x  8 KB  ( 64 rows x 64 bf16, swizzled)
  char* Asc = (char*)AsRaw;
  char* Bsc = (char*)BsRaw;

  const int tid  = threadIdx.x;
  const int lane = tid & 63;
  const int w    = tid >> 6;      // wave 0..3, owns G rows [32w, 32w+32)
  const int cl   = lane & 15;
  const int g    = lane >> 4;
  const int yblk = blockIdx.x;
  const int bb   = blockIdx.y;

  f4v acc[2][4];
  float runM[2][2], runD[2][2], runN[2][2];
  #pragma unroll
  for (int mi = 0; mi < 2; ++mi)
    #pragma unroll
    for (int p = 0; p < 2; ++p) { runM[mi][p] = -1e30f; runD[mi][p] = 0.f; runN[mi][p] = 0.f; }

  uint4 ra[4], rb[2];

  auto loadA = [&](int kk) {
    #pragma unroll
    for (int i = 0; i < 4; ++i) {
      int c = tid + i * 256; int r = c >> 3, sl = c & 7;
      if constexpr (PRE) {
        ra[i] = *(const uint4*)(Gb + ((size_t)(yblk * MR + r) * ND + kk * BK + sl * 8));
      } else {
        int grow = yblk * MR + r; int y = grow >> 1;
        if (y < NY) {
          const float* src = (grow & 1) ? Wf : Uf;
          const float4* p = (const float4*)(src + (size_t)y * ND + kk * BK + sl * 8);
          float4 f0 = p[0], f1 = p[1];
          ra[i] = make_uint4(pk2(f0.x, f0.y), pk2(f0.z, f0.w), pk2(f1.x, f1.y), pk2(f1.z, f1.w));
        } else ra[i] = make_uint4(0u, 0u, 0u, 0u);
      }
    }
  };
  auto loadB = [&](int t, int kk) {
    #pragma unroll
    for (int i = 0; i < 2; ++i) {
      int c = tid + i * 256; int lr = c >> 3, sl = c & 7;
      if constexpr (PRE) {
        rb[i] = *(const uint4*)(xb + ((size_t)(bb * LPAD + t * BN + lr) * ND + kk * BK + sl * 8));
      } else {
        int l = t * BN + lr;
        if (l < NL) {
          const float4* p = (const float4*)(xf + ((size_t)bb * NL + l) * ND + kk * BK + sl * 8);
          float4 f0 = p[0], f1 = p[1];
          rb[i] = make_uint4(pk2(f0.x, f0.y), pk2(f0.z, f0.w), pk2(f1.x, f1.y), pk2(f1.z, f1.w));
        } else rb[i] = make_uint4(0u, 0u, 0u, 0u);
      }
    }
  };
  auto writeStage = [&](int buf) {
    #pragma unroll
    for (int i = 0; i < 4; ++i) {
      int c = tid + i * 256; int r = c >> 3, sl = c & 7;
      *(uint4*)(Asc + buf * 16384 + r * 128 + ((sl * 16) ^ ((r & 7) << 4))) = ra[i];
    }
    #pragma unroll
    for (int i = 0; i < 2; ++i) {
      int c = tid + i * 256; int lr = c >> 3, sl = c & 7;
      *(uint4*)(Bsc + buf * 8192 + lr * 128 + ((sl * 16) ^ ((lr & 7) << 4))) = rb[i];
    }
  };

  // prologue: stage step 0 into buf 0
  loadA(0); loadB(0, 0); writeStage(0);

  for (int t = 0; t < NLT; ++t) {
    #pragma unroll
    for (int mi = 0; mi < 2; ++mi)
      #pragma unroll
      for (int ni = 0; ni < 4; ++ni)
        #pragma unroll
        for (int q = 0; q < 4; ++q) acc[mi][ni][q] = 0.f;

    for (int kk = 0; kk < NKK; ++kk) {
      const int s = t * NKK + kk;
      const int buf = s & 1;
      __syncthreads();
      const bool hn = (s + 1) < NSTEP;
      if (hn) { int s1 = s + 1; loadA(s1 & 7); loadB(s1 >> 3, s1 & 7); }

      #pragma unroll
      for (int kf = 0; kf < 2; ++kf) {
        s8v af[2], bv[4];
        #pragma unroll
        for (int mi = 0; mi < 2; ++mi) {
          int r  = w * 32 + mi * 16 + cl;
          int kb = kf * 64 + g * 16;
          af[mi] = *(const s8v*)(Asc + buf * 16384 + r * 128 + (kb ^ ((r & 7) << 4)));
        }
        #pragma unroll
        for (int ni = 0; ni < 4; ++ni) {
          int lr = ni * 16 + cl;
          int kb = kf * 64 + g * 16;
          bv[ni] = *(const s8v*)(Bsc + buf * 8192 + lr * 128 + (kb ^ ((lr & 7) << 4)));
        }
        #pragma unroll
        for (int mi = 0; mi < 2; ++mi)
          #pragma unroll
          for (int ni = 0; ni < 4; ++ni)
            acc[mi][ni] = __builtin_amdgcn_mfma_f32_16x16x32_bf16(af[mi], bv[ni], acc[mi][ni], 0, 0, 0);
      }

      if (hn) writeStage(buf ^ 1);
    }

    // ---- online-softmax epilogue for l-tile t (registers + 16-lane shuffles only)
    #pragma unroll
    for (int mi = 0; mi < 2; ++mi) {
      #pragma unroll
      for (int p = 0; p < 2; ++p) {
        float sv[4], tv[4], mloc = -1e30f;
        #pragma unroll
        for (int ni = 0; ni < 4; ++ni) {
          bool valid = (t * BN + ni * 16 + cl) < NL;
          float s_ = acc[mi][ni][2 * p];
          sv[ni] = valid ? s_ : -1e30f;
          tv[ni] = acc[mi][ni][2 * p + 1];
          mloc = fmaxf(mloc, sv[ni]);
        }
        #pragma unroll
        for (int off = 1; off < 16; off <<= 1) mloc = fmaxf(mloc, __shfl_xor(mloc, off));
        float newM = fmaxf(runM[mi][p], mloc);
        float se = 0.f, ste = 0.f;
        #pragma unroll
        for (int ni = 0; ni < 4; ++ni) {
          float e = __expf(sv[ni] - newM);
          se += e; ste += e * tv[ni];
        }
        #pragma unroll
        for (int off = 1; off < 16; off <<= 1) { se += __shfl_xor(se, off); ste += __shfl_xor(ste, off); }
        float sc = __expf(runM[mi][p] - newM);
        runD[mi][p] = runD[mi][p] * sc + se;
        runN[mi][p] = runN[mi][p] * sc + ste;
        runM[mi][p] = newM;
      }
    }
  }

  // ---- store: lanes with cl==0 own 4 labels each (per g), 64 labels/block
  if (cl == 0) {
    #pragma unroll
    for (int mi = 0; mi < 2; ++mi) {
      #pragma unroll
      for (int p = 0; p < 2; ++p) {
        int yloc = w * 16 + mi * 8 + 2 * g + p;
        int y = yblk * YTL + yloc;
        if (y < NY) out[(size_t)bb * NY + y] = runN[mi][p] / runD[mi][p] + bias[y];
      }
    }
  }
}

extern "C" void kernel_launch(void* const* d_in, const int* in_sizes, int n_in,
                              void* d_out, int out_size, void* d_ws, size_t ws_size,
                              hipStream_t stream) {
  const float* xf   = (const float*)d_in[0];
  const float* Uf   = (const float*)d_in[1];
  const float* Wf   = (const float*)d_in[2];
  const float* bias = (const float*)d_in[3];
  float* out = (float*)d_out;

  const size_t need = GB_BYTES + XB_BYTES;   // ~39.3 MB
  if (ws_size >= need) {
    unsigned short* Gb = (unsigned short*)d_ws;
    unsigned short* xb = (unsigned short*)((char*)d_ws + GB_BYTES);
    // G: RPAD*ND/8 chunks / 256 thr = 4480 blocks ; x: NB*LPAD*ND/8/256 = 5120
    cvt_g_kernel<<<4480, 256, 0, stream>>>(Uf, Wf, Gb);
    cvt_x_kernel<<<5120, 256, 0, stream>>>(xf, xb);
    fused_kernel<true><<<dim3(NYB, NB), 256, 0, stream>>>(xf, Uf, Wf, bias, Gb, xb, out);
  } else {
    fused_kernel<false><<<dim3(NYB, NB), 256, 0, stream>>>(xf, Uf, Wf, bias, nullptr, nullptr, out);
  }
}

// Round 2
// 608.744 us; speedup vs baseline: 4.2388x; 4.2388x over previous
//
#include <hip/hip_runtime.h>
#include <hip/hip_bf16.h>

// Problem constants
#define NB 8
#define NL 2500
#define ND 512
#define NY 8921

// Tiling
#define LPAD 2560          // l padded: 20 * 128
#define BN   128           // l-tile
#define NLT  20            // LPAD/BN
#define NKK  8             // ND/64
#define NSTEP 160          // NLT*NKK
#define MR   128           // G rows per block (64 labels, U/W interleaved)
#define YTL  64
#define NYB  140           // ceil(8921/64)
#define RPAD 17920         // NYB*MR

#define TILE_BYTES 16384   // 128 rows x 64 bf16 (128B), swizzled
#define GT_BYTES ((size_t)NYB * NKK * TILE_BYTES)        // 18,350,080
#define XT_BYTES ((size_t)NB * NLT * NKK * TILE_BYTES)   // 20,971,520

typedef short s8v __attribute__((ext_vector_type(8)));
typedef float f4v __attribute__((ext_vector_type(4)));

__device__ __forceinline__ unsigned short f2bf(float f) {
  unsigned int u = __float_as_uint(f);
  return (unsigned short)((u + 0x7FFFu + ((u >> 16) & 1u)) >> 16);
}
__device__ __forceinline__ unsigned int pk2(float a, float b) {
  return (unsigned int)f2bf(a) | ((unsigned int)f2bf(b) << 16);
}

__device__ __forceinline__ void async_copy16(const char* g, char* l) {
  __builtin_amdgcn_global_load_lds(
      (const __attribute__((address_space(1))) void*)g,
      (__attribute__((address_space(3))) void*)l, 16, 0, 0);
}

// ---- G: interleave U/W rows (row 2y = U[y], 2y+1 = W[y]), bf16, pre-tiled
// layout: [yblk 140][kk 8][tile 16KB], tile row r: granule gn at r*128 + ((gn^(r&7))*16)
__global__ void cvt_g_kernel(const float* __restrict__ U, const float* __restrict__ W,
                             char* __restrict__ Gt) {
  int c = blockIdx.x * 256 + threadIdx.x;        // one 16B granule each
  int gn = c & 7;
  int kk = (c >> 3) & 7;
  int rg = c >> 6;                                // global G row 0..17919
  int yblk = rg >> 7, r = rg & 127;
  int y = rg >> 1;
  uint4 o;
  if (y < NY) {
    const float* src = (rg & 1) ? W : U;
    const float4* p = (const float4*)(src + (size_t)y * ND + kk * 64 + gn * 8);
    float4 f0 = p[0], f1 = p[1];
    o.x = pk2(f0.x, f0.y); o.y = pk2(f0.z, f0.w);
    o.z = pk2(f1.x, f1.y); o.w = pk2(f1.z, f1.w);
  } else {
    o = make_uint4(0u, 0u, 0u, 0u);
  }
  size_t off = ((size_t)(yblk * NKK + kk)) * TILE_BYTES
             + (size_t)r * 128 + ((gn ^ (r & 7)) << 4);
  *(uint4*)(Gt + off) = o;
}

// ---- x -> bf16, pre-tiled: [b 8][t 20][kk 8][tile 16KB], zero-padded l>=2500
__global__ void cvt_x_kernel(const float* __restrict__ x, char* __restrict__ Xt) {
  int c = blockIdx.x * 256 + threadIdx.x;
  int gn = c & 7;
  int kk = (c >> 3) & 7;
  int row = c >> 6;                               // b*LPAD + l
  int b = row / LPAD;
  int l = row - b * LPAD;
  int t = l >> 7, r = l & 127;
  uint4 o;
  if (l < NL) {
    const float4* p = (const float4*)(x + ((size_t)b * NL + l) * ND + kk * 64 + gn * 8);
    float4 f0 = p[0], f1 = p[1];
    o.x = pk2(f0.x, f0.y); o.y = pk2(f0.z, f0.w);
    o.z = pk2(f1.x, f1.y); o.w = pk2(f1.z, f1.w);
  } else {
    o = make_uint4(0u, 0u, 0u, 0u);
  }
  size_t off = ((size_t)((b * NLT + t) * NKK + kk)) * TILE_BYTES
             + (size_t)r * 128 + ((gn ^ (r & 7)) << 4);
  *(uint4*)(Xt + off) = o;
}

// ---- fused dual-GEMM + online softmax + weighted reduce
// block: 128 G-rows (64 labels) x 128 l, 4 waves in 2x2 grid of 64x64 tiles
__global__ __launch_bounds__(256, 2) void fused_kernel(
    const char* __restrict__ Gt, const char* __restrict__ Xt,
    const float* __restrict__ bias, float* __restrict__ out)
{
  __shared__ uint4 AsRaw[2][1024];   // 2 x 16KB swizzled A (G) tiles
  __shared__ uint4 BsRaw[2][1024];   // 2 x 16KB swizzled B (x) tiles
  char* AsC = (char*)AsRaw;
  char* BsC = (char*)BsRaw;

  const int tid  = threadIdx.x;
  const int lane = tid & 63;
  const int w    = tid >> 6;
  const int wr   = w >> 1, wc = w & 1;
  const int cl   = lane & 15, g = lane >> 4;
  const int id   = blockIdx.x;
  const int bb   = id & 7;        // batch == XCD (round-robin by linear id)
  const int yblk = id >> 3;

  const char* gA0 = Gt + (size_t)yblk * NKK * TILE_BYTES;
  const char* gB0 = Xt + (size_t)bb * NLT * NKK * TILE_BYTES;

  f4v acc[4][4];
  float runM[4][2], runD[4][2], runN[4][2];
  #pragma unroll
  for (int mi = 0; mi < 4; ++mi)
    #pragma unroll
    for (int p = 0; p < 2; ++p) { runM[mi][p] = -1e30f; runD[mi][p] = 0.f; runN[mi][p] = 0.f; }

  auto stage = [&](int buf, int s) {
    int t = s >> 3, kk = s & 7;
    const char* ga = gA0 + (size_t)kk * TILE_BYTES;
    const char* gb = gB0 + (size_t)(t * NKK + kk) * TILE_BYTES;
    #pragma unroll
    for (int i = 0; i < 4; ++i) {
      int ch = (w * 4 + i) << 10;                 // 1KB chunk per wave-instr
      async_copy16(ga + ch + lane * 16, AsC + buf * TILE_BYTES + ch);
      async_copy16(gb + ch + lane * 16, BsC + buf * TILE_BYTES + ch);
    }
  };

  stage(0, 0);
  __syncthreads();

  for (int t = 0; t < NLT; ++t) {
    #pragma unroll
    for (int mi = 0; mi < 4; ++mi)
      #pragma unroll
      for (int ni = 0; ni < 4; ++ni)
        #pragma unroll
        for (int q = 0; q < 4; ++q) acc[mi][ni][q] = 0.f;

    for (int kk = 0; kk < NKK; ++kk) {
      const int s = t * NKK + kk;
      const int buf = s & 1;
      if (s + 1 < NSTEP) stage(buf ^ 1, s + 1);   // prefetch hides under MFMA

      #pragma unroll
      for (int kf = 0; kf < 2; ++kf) {
        s8v af[4], bv[4];
        const int kb = kf * 64 + g * 16;
        const int sw = (cl & 7) << 4;
        #pragma unroll
        for (int mi = 0; mi < 4; ++mi) {
          int row = wr * 64 + mi * 16 + cl;
          af[mi] = *(const s8v*)(AsC + buf * TILE_BYTES + row * 128 + (kb ^ sw));
        }
        #pragma unroll
        for (int ni = 0; ni < 4; ++ni) {
          int row = wc * 64 + ni * 16 + cl;
          bv[ni] = *(const s8v*)(BsC + buf * TILE_BYTES + row * 128 + (kb ^ sw));
        }
        #pragma unroll
        for (int mi = 0; mi < 4; ++mi)
          #pragma unroll
          for (int ni = 0; ni < 4; ++ni)
            acc[mi][ni] = __builtin_amdgcn_mfma_f32_16x16x32_bf16(af[mi], bv[ni], acc[mi][ni], 0, 0, 0);
      }
      __syncthreads();   // drains prefetch (vmcnt) + protects buf swap
    }

    // ---- online-softmax update for l-tile t (registers + 16-lane shuffles)
    #pragma unroll
    for (int mi = 0; mi < 4; ++mi) {
      #pragma unroll
      for (int p = 0; p < 2; ++p) {
        float sv[4], tv[4], mloc = -1e30f;
        #pragma unroll
        for (int ni = 0; ni < 4; ++ni) {
          bool valid = (t * BN + wc * 64 + ni * 16 + cl) < NL;
          sv[ni] = valid ? acc[mi][ni][2 * p] : -1e30f;
          tv[ni] = acc[mi][ni][2 * p + 1];
          mloc = fmaxf(mloc, sv[ni]);
        }
        #pragma unroll
        for (int off = 1; off < 16; off <<= 1) mloc = fmaxf(mloc, __shfl_xor(mloc, off));
        float newM = fmaxf(runM[mi][p], mloc);
        float se = 0.f, ste = 0.f;
        #pragma unroll
        for (int ni = 0; ni < 4; ++ni) {
          float e = __expf(sv[ni] - newM);
          se += e; ste += e * tv[ni];
        }
        #pragma unroll
        for (int off = 1; off < 16; off <<= 1) { se += __shfl_xor(se, off); ste += __shfl_xor(ste, off); }
        float sc = __expf(runM[mi][p] - newM);
        runD[mi][p] = runD[mi][p] * sc + se;
        runN[mi][p] = runN[mi][p] * sc + ste;
        runM[mi][p] = newM;
      }
    }
  }

  // ---- merge wc=1 half into wc=0 via LDS (flash-state merge), then store
  __syncthreads();
  float* mb = (float*)AsRaw;     // [wr*32 + lab] * 3
  if (wc == 1 && cl == 0) {
    #pragma unroll
    for (int mi = 0; mi < 4; ++mi)
      #pragma unroll
      for (int p = 0; p < 2; ++p) {
        int lab = 8 * mi + 2 * g + p;
        int idx = (wr * 32 + lab) * 3;
        mb[idx] = runM[mi][p]; mb[idx + 1] = runD[mi][p]; mb[idx + 2] = runN[mi][p];
      }
  }
  __syncthreads();
  if (wc == 0 && cl == 0) {
    #pragma unroll
    for (int mi = 0; mi < 4; ++mi)
      #pragma unroll
      for (int p = 0; p < 2; ++p) {
        int lab = 8 * mi + 2 * g + p;
        int idx = (wr * 32 + lab) * 3;
        float M1 = mb[idx], D1 = mb[idx + 1], N1 = mb[idx + 2];
        float M0 = runM[mi][p], D0 = runD[mi][p], N0 = runN[mi][p];
        float M = fmaxf(M0, M1);
        float e0 = __expf(M0 - M), e1 = __expf(M1 - M);
        float D = D0 * e0 + D1 * e1;
        float N = N0 * e0 + N1 * e1;
        int y = yblk * YTL + wr * 32 + lab;
        if (y < NY) out[(size_t)bb * NY + y] = N / D + bias[y];
      }
  }
}

extern "C" void kernel_launch(void* const* d_in, const int* in_sizes, int n_in,
                              void* d_out, int out_size, void* d_ws, size_t ws_size,
                              hipStream_t stream) {
  const float* xf   = (const float*)d_in[0];
  const float* Uf   = (const float*)d_in[1];
  const float* Wf   = (const float*)d_in[2];
  const float* bias = (const float*)d_in[3];
  float* out = (float*)d_out;

  char* Gt = (char*)d_ws;
  char* Xt = (char*)d_ws + GT_BYTES;

  // G granules: 17920 rows * 64 = 1,146,880 / 256 = 4480 blocks
  cvt_g_kernel<<<4480, 256, 0, stream>>>(Uf, Wf, Gt);
  // x granules: 8*2560 rows * 64 = 1,310,720 / 256 = 5120 blocks
  cvt_x_kernel<<<5120, 256, 0, stream>>>(xf, Xt);
  // 1120 blocks: id&7 = batch (XCD-pinned), id>>3 = yblk
  fused_kernel<<<NYB * NB, 256, 0, stream>>>(Gt, Xt, bias, out);
}

// Round 3
// 534.784 us; speedup vs baseline: 4.8250x; 1.1383x over previous
//
#include <hip/hip_runtime.h>
#include <hip/hip_bf16.h>

// Problem constants
#define NB 8
#define NL 2500
#define ND 512
#define NY 8921

// Tiling
#define BM 256             // G rows per block (128 labels, U/W interleaved)
#define BN 256             // l-tile
#define BK 64
#define NKK 8              // ND/BK
#define LPAD 2560          // 10 * 256
#define NLT 10             // LPAD/BN
#define NYB 70             // ceil(NY/128)
#define YPAD 8960          // NYB*128
#define RPAD 17920         // NYB*BM

#define SPLIT 5            // l-range splits (2 l-tiles per block)
#define LSPL_MAIN 2

#define TILE 32768         // 256 rows x 64 bf16 (128B/row), swizzled image
#define GT_BYTES ((size_t)NYB * NKK * TILE)          // 18,350,080
#define XT_BYTES ((size_t)NB * NLT * NKK * TILE)     // 20,971,520
#define P_ELEMS  ((size_t)SPLIT * NB * YPAD)         // 358,400
#define P_BYTES  (P_ELEMS * 4)

typedef short s8v __attribute__((ext_vector_type(8)));
typedef float f4v __attribute__((ext_vector_type(4)));

__device__ __forceinline__ unsigned short f2bf(float f) {
  unsigned int u = __float_as_uint(f);
  return (unsigned short)((u + 0x7FFFu + ((u >> 16) & 1u)) >> 16);
}
__device__ __forceinline__ unsigned int pk2(float a, float b) {
  return (unsigned int)f2bf(a) | ((unsigned int)f2bf(b) << 16);
}
__device__ __forceinline__ void async_copy16(const char* g, char* l) {
  __builtin_amdgcn_global_load_lds(
      (const __attribute__((address_space(1))) void*)g,
      (__attribute__((address_space(3))) void*)l, 16, 0, 0);
}

// ---- G: interleave U/W rows (row 2y=U[y], 2y+1=W[y]) -> bf16 swizzled tiles
// layout [yblk 70][kk 8][tile 32KB]; tile row r: granule gn at r*128 + ((gn^(r&7))<<4)
// grid: 4480 = 8 kk-groups x 560; within group, wave writes 1KB contiguous
__global__ void cvt_g_kernel(const float* __restrict__ U, const float* __restrict__ W,
                             char* __restrict__ Gt) {
  int kk = blockIdx.x / 560;
  int c  = (blockIdx.x - kk * 560) * 256 + threadIdx.x;   // [0, 143360)
  int gn = c & 7;
  int rg = c >> 3;                 // global G row 0..17919
  int yblk = rg >> 8, r = rg & 255;
  int y = rg >> 1;
  uint4 o;
  if (y < NY) {
    const float* src = (rg & 1) ? W : U;
    const float4* p = (const float4*)(src + (size_t)y * ND + kk * 64 + gn * 8);
    float4 f0 = p[0], f1 = p[1];
    o.x = pk2(f0.x, f0.y); o.y = pk2(f0.z, f0.w);
    o.z = pk2(f1.x, f1.y); o.w = pk2(f1.z, f1.w);
  } else {
    o = make_uint4(0u, 0u, 0u, 0u);
  }
  size_t off = (size_t)(yblk * NKK + kk) * TILE + (size_t)r * 128 + ((gn ^ (r & 7)) << 4);
  *(uint4*)(Gt + off) = o;
}

// ---- x -> bf16 swizzled tiles: [b 8][t 10][kk 8][tile 32KB], zero-pad l>=2500
// grid: 5120 = 8 kk-groups x 640
__global__ void cvt_x_kernel(const float* __restrict__ x, char* __restrict__ Xt) {
  int kk = blockIdx.x / 640;
  int c  = (blockIdx.x - kk * 640) * 256 + threadIdx.x;   // [0, 163840)
  int gn = c & 7;
  int row = c >> 3;                // b*LPAD + l, 0..20479
  int b = row / LPAD;
  int l = row - b * LPAD;
  int t = l >> 8, r = l & 255;
  uint4 o;
  if (l < NL) {
    const float4* p = (const float4*)(x + ((size_t)b * NL + l) * ND + kk * 64 + gn * 8);
    float4 f0 = p[0], f1 = p[1];
    o.x = pk2(f0.x, f0.y); o.y = pk2(f0.z, f0.w);
    o.z = pk2(f1.x, f1.y); o.w = pk2(f1.z, f1.w);
  } else {
    o = make_uint4(0u, 0u, 0u, 0u);
  }
  size_t off = (size_t)((b * NLT + t) * NKK + kk) * TILE + (size_t)r * 128 + ((gn ^ (r & 7)) << 4);
  *(uint4*)(Xt + off) = o;
}

// ---- fused dual-GEMM + online softmax; 512 thr = 8 waves (2M x 4N), 256x256 tile
template<int LSPL, bool PARTIAL>
__global__ __launch_bounds__(512, 2) void fused_kernel(
    const char* __restrict__ Gt, const char* __restrict__ Xt,
    const float* __restrict__ bias, float* __restrict__ out,
    float* __restrict__ PM, float* __restrict__ PD, float* __restrict__ PN)
{
  __shared__ uint4 AsRaw[2 * TILE / 16];   // 64 KB
  __shared__ uint4 BsRaw[2 * TILE / 16];   // 64 KB
  char* AsC = (char*)AsRaw;
  char* BsC = (char*)BsRaw;

  const int tid  = threadIdx.x;
  const int lane = tid & 63;
  const int w    = tid >> 6;        // 0..7
  const int wr   = w >> 2;          // 0..1  M-half
  const int wc   = w & 3;           // 0..3  N-quarter
  const int cl   = lane & 15, g = lane >> 4;

  const int id    = blockIdx.x;
  const int bb    = id & 7;         // batch, XCD-pinned by round-robin dispatch
  const int n     = id >> 3;
  const int split = n / NYB;
  const int yblk  = n - split * NYB;
  const int tbase = split * LSPL;

  const char* GA = Gt + (size_t)yblk * NKK * TILE;
  const char* XB = Xt + ((size_t)bb * NLT + tbase) * NKK * TILE;

  f4v acc[8][4];
  float runM[8][2], runD[8][2], runN[8][2];
  #pragma unroll
  for (int mi = 0; mi < 8; ++mi)
    #pragma unroll
    for (int p = 0; p < 2; ++p) { runM[mi][p] = -1e30f; runD[mi][p] = 0.f; runN[mi][p] = 0.f; }

  const int soff = w * 1024 + lane * 16;
  auto stageAll = [&](int buf, int u) {
    const char* ga = GA + (size_t)(u & 7) * TILE;
    const char* gb = XB + (size_t)u * TILE;         // X layout [t][kk] contiguous
    #pragma unroll
    for (int i = 0; i < 4; ++i) {
      async_copy16(ga + i * 8192 + soff, AsC + buf * TILE + i * 8192 + w * 1024);
      async_copy16(gb + i * 8192 + soff, BsC + buf * TILE + i * 8192 + w * 1024);
    }
  };

  // prologue
  stageAll(0, 0);
  asm volatile("s_waitcnt vmcnt(0)" ::: "memory");
  __builtin_amdgcn_s_barrier();
  asm volatile("" ::: "memory");

  for (int t = 0; t < LSPL; ++t) {
    #pragma unroll
    for (int mi = 0; mi < 8; ++mi)
      #pragma unroll
      for (int ni = 0; ni < 4; ++ni)
        #pragma unroll
        for (int q = 0; q < 4; ++q) acc[mi][ni][q] = 0.f;

    for (int kk = 0; kk < NKK; ++kk) {
      const int u = t * NKK + kk;
      const int cur = u & 1;
      const char* A = AsC + cur * TILE;
      const char* B = BsC + cur * TILE;

      // issue next K-step staging first: max latency cover before boundary drain
      if (u + 1 < LSPL * NKK) stageAll(cur ^ 1, u + 1);

      s8v bv[4][2];
      #pragma unroll
      for (int ni = 0; ni < 4; ++ni)
        #pragma unroll
        for (int kf = 0; kf < 2; ++kf) {
          int r = wc * 64 + ni * 16 + cl;
          bv[ni][kf] = *(const s8v*)(B + r * 128 + ((kf * 64 + g * 16) ^ ((r & 7) << 4)));
        }

      #pragma unroll
      for (int ph = 0; ph < 4; ++ph) {
        s8v af[2][2];
        #pragma unroll
        for (int j = 0; j < 2; ++j)
          #pragma unroll
          for (int kf = 0; kf < 2; ++kf) {
            int r = wr * 128 + (ph * 2 + j) * 16 + cl;
            af[j][kf] = *(const s8v*)(A + r * 128 + ((kf * 64 + g * 16) ^ ((r & 7) << 4)));
          }
        __builtin_amdgcn_s_barrier();             // align waves: reads done, MFMA next
        __builtin_amdgcn_s_setprio(1);
        #pragma unroll
        for (int kf = 0; kf < 2; ++kf)
          #pragma unroll
          for (int j = 0; j < 2; ++j)
            #pragma unroll
            for (int ni = 0; ni < 4; ++ni)
              acc[ph * 2 + j][ni] = __builtin_amdgcn_mfma_f32_16x16x32_bf16(
                  af[j][kf], bv[ni][kf], acc[ph * 2 + j][ni], 0, 0, 0);
        __builtin_amdgcn_s_setprio(0);
        if (ph < 3) __builtin_amdgcn_s_barrier();
      }

      // ---- per-l-tile online-softmax (register + 16-lane shuffles), hides vmcnt drain
      if (kk == NKK - 1) {
        const int lbase = (tbase + t) * BN + wc * 64 + cl;
        #pragma unroll
        for (int mi = 0; mi < 8; ++mi) {
          #pragma unroll
          for (int p = 0; p < 2; ++p) {
            float sv[4], tv[4], mloc = -1e30f;
            #pragma unroll
            for (int ni = 0; ni < 4; ++ni) {
              bool valid = (lbase + ni * 16) < NL;
              sv[ni] = valid ? acc[mi][ni][2 * p] : -1e30f;
              tv[ni] = acc[mi][ni][2 * p + 1];
              mloc = fmaxf(mloc, sv[ni]);
            }
            #pragma unroll
            for (int off = 1; off < 16; off <<= 1) mloc = fmaxf(mloc, __shfl_xor(mloc, off));
            float newM = fmaxf(runM[mi][p], mloc);
            float se = 0.f, ste = 0.f;
            #pragma unroll
            for (int ni = 0; ni < 4; ++ni) {
              float e = __expf(sv[ni] - newM);
              se += e; ste += e * tv[ni];
            }
            #pragma unroll
            for (int off = 1; off < 16; off <<= 1) { se += __shfl_xor(se, off); ste += __shfl_xor(ste, off); }
            float sc = __expf(runM[mi][p] - newM);
            runD[mi][p] = runD[mi][p] * sc + se;
            runN[mi][p] = runN[mi][p] * sc + ste;
            runM[mi][p] = newM;
          }
        }
      }

      // K-step boundary: drain staging, switch buffers
      asm volatile("s_waitcnt vmcnt(0)" ::: "memory");
      __builtin_amdgcn_s_barrier();
      asm volatile("" ::: "memory");
    }
  }

  // ---- 4-way wc merge via LDS, then write partials / output
  __syncthreads();
  float* sm = (float*)AsRaw;     // 128 labels x 4 wc x 3 floats = 6 KB
  if (cl == 0) {
    #pragma unroll
    for (int mi = 0; mi < 8; ++mi)
      #pragma unroll
      for (int p = 0; p < 2; ++p) {
        int lab = wr * 64 + mi * 8 + 2 * g + p;   // 0..127
        float* s3 = sm + (lab * 4 + wc) * 3;
        s3[0] = runM[mi][p]; s3[1] = runD[mi][p]; s3[2] = runN[mi][p];
      }
  }
  __syncthreads();
  if (tid < 128) {
    float M = -1e30f, D = 0.f, N = 0.f;
    #pragma unroll
    for (int q = 0; q < 4; ++q) {
      const float* s3 = sm + (tid * 4 + q) * 3;
      float M1 = s3[0], D1 = s3[1], N1 = s3[2];
      float Mn = fmaxf(M, M1);
      float e0 = __expf(M - Mn), e1 = __expf(M1 - Mn);
      D = D * e0 + D1 * e1;
      N = N * e0 + N1 * e1;
      M = Mn;
    }
    int y = yblk * 128 + tid;
    if constexpr (PARTIAL) {
      size_t o = ((size_t)split * NB + bb) * YPAD + y;
      PM[o] = M; PD[o] = D; PN[o] = N;
    } else {
      if (y < NY) out[(size_t)bb * NY + y] = N / D + bias[y];
    }
  }
}

// ---- merge SPLIT partials + bias -> out
__global__ void merge_kernel(const float* __restrict__ PM, const float* __restrict__ PD,
                             const float* __restrict__ PN, const float* __restrict__ bias,
                             float* __restrict__ out) {
  int idx = blockIdx.x * 256 + threadIdx.x;      // NB*YPAD
  int b = idx / YPAD, y = idx - b * YPAD;
  if (y >= NY) return;
  float M = -1e30f, D = 0.f, N = 0.f;
  #pragma unroll
  for (int s = 0; s < SPLIT; ++s) {
    size_t o = ((size_t)s * NB + b) * YPAD + y;
    float M1 = PM[o], D1 = PD[o], N1 = PN[o];
    float Mn = fmaxf(M, M1);
    float e0 = __expf(M - Mn), e1 = __expf(M1 - Mn);
    D = D * e0 + D1 * e1;
    N = N * e0 + N1 * e1;
    M = Mn;
  }
  out[(size_t)b * NY + y] = N / D + bias[y];
}

extern "C" void kernel_launch(void* const* d_in, const int* in_sizes, int n_in,
                              void* d_out, int out_size, void* d_ws, size_t ws_size,
                              hipStream_t stream) {
  const float* xf   = (const float*)d_in[0];
  const float* Uf   = (const float*)d_in[1];
  const float* Wf   = (const float*)d_in[2];
  const float* bias = (const float*)d_in[3];
  float* out = (float*)d_out;

  char* Gt = (char*)d_ws;
  char* Xt = Gt + GT_BYTES;
  float* PM = (float*)(Xt + XT_BYTES);
  float* PD = PM + P_ELEMS;
  float* PN = PD + P_ELEMS;

  cvt_g_kernel<<<4480, 256, 0, stream>>>(Uf, Wf, Gt);
  cvt_x_kernel<<<5120, 256, 0, stream>>>(xf, Xt);

  const size_t need_main = GT_BYTES + XT_BYTES + 3 * P_BYTES;   // ~43.6 MB
  if (ws_size >= need_main) {
    fused_kernel<LSPL_MAIN, true><<<NYB * NB * SPLIT, 512, 0, stream>>>(
        Gt, Xt, bias, out, PM, PD, PN);
    merge_kernel<<<NB * YPAD / 256, 256, 0, stream>>>(PM, PD, PN, bias, out);
  } else {
    fused_kernel<NLT, false><<<NYB * NB, 512, 0, stream>>>(
        Gt, Xt, bias, out, PM, PD, PN);
  }
}

// Round 4
// 505.727 us; speedup vs baseline: 5.1022x; 1.0575x over previous
//
#include <hip/hip_runtime.h>
#include <hip/hip_bf16.h>

// Problem constants
#define NB 8
#define NL 2500
#define ND 512
#define NY 8921

// Tiling
#define BM 256             // G rows per block (128 labels, U/W interleaved)
#define BN 256             // l-tile
#define BK 64
#define NKK 8              // ND/BK
#define LPAD 2560          // 10 * 256
#define NLT 10             // LPAD/BN
#define NYB 70             // ceil(NY/128)
#define YPAD 8960          // NYB*128
#define RPAD 17920         // NYB*BM

#define SPLIT 5            // l-range splits (2 l-tiles per block)
#define LSPL_MAIN 2

#define TILE 32768         // 256 rows x 64 bf16 (128B/row), swizzled image
#define GT_BYTES ((size_t)NYB * NKK * TILE)          // 18,350,080
#define XT_BYTES ((size_t)NB * NLT * NKK * TILE)     // 20,971,520
#define P_ELEMS  ((size_t)SPLIT * NB * YPAD)         // 358,400
#define P_BYTES  (P_ELEMS * 4)

typedef short s8v __attribute__((ext_vector_type(8)));
typedef float f4v __attribute__((ext_vector_type(4)));

__device__ __forceinline__ unsigned short f2bf(float f) {
  unsigned int u = __float_as_uint(f);
  return (unsigned short)((u + 0x7FFFu + ((u >> 16) & 1u)) >> 16);
}
__device__ __forceinline__ unsigned int pk2(float a, float b) {
  return (unsigned int)f2bf(a) | ((unsigned int)f2bf(b) << 16);
}
__device__ __forceinline__ void async_copy16(const char* g, char* l) {
  __builtin_amdgcn_global_load_lds(
      (const __attribute__((address_space(1))) void*)g,
      (__attribute__((address_space(3))) void*)l, 16, 0, 0);
}

// ---- G: interleave U/W rows (row 2y=U[y], 2y+1=W[y]) -> bf16 swizzled tiles
// layout [yblk 70][kk 8][tile 32KB]; tile row r: granule gn at r*128 + ((gn^(r&7))<<4)
__global__ void cvt_g_kernel(const float* __restrict__ U, const float* __restrict__ W,
                             char* __restrict__ Gt) {
  int kk = blockIdx.x / 560;
  int c  = (blockIdx.x - kk * 560) * 256 + threadIdx.x;   // [0, 143360)
  int gn = c & 7;
  int rg = c >> 3;                 // global G row 0..17919
  int yblk = rg >> 8, r = rg & 255;
  int y = rg >> 1;
  uint4 o;
  if (y < NY) {
    const float* src = (rg & 1) ? W : U;
    const float4* p = (const float4*)(src + (size_t)y * ND + kk * 64 + gn * 8);
    float4 f0 = p[0], f1 = p[1];
    o.x = pk2(f0.x, f0.y); o.y = pk2(f0.z, f0.w);
    o.z = pk2(f1.x, f1.y); o.w = pk2(f1.z, f1.w);
  } else {
    o = make_uint4(0u, 0u, 0u, 0u);
  }
  size_t off = (size_t)(yblk * NKK + kk) * TILE + (size_t)r * 128 + ((gn ^ (r & 7)) << 4);
  *(uint4*)(Gt + off) = o;
}

// ---- x -> bf16 swizzled tiles: [b 8][t 10][kk 8][tile 32KB], zero-pad l>=2500
__global__ void cvt_x_kernel(const float* __restrict__ x, char* __restrict__ Xt) {
  int kk = blockIdx.x / 640;
  int c  = (blockIdx.x - kk * 640) * 256 + threadIdx.x;   // [0, 163840)
  int gn = c & 7;
  int row = c >> 3;                // b*LPAD + l, 0..20479
  int b = row / LPAD;
  int l = row - b * LPAD;
  int t = l >> 8, r = l & 255;
  uint4 o;
  if (l < NL) {
    const float4* p = (const float4*)(x + ((size_t)b * NL + l) * ND + kk * 64 + gn * 8);
    float4 f0 = p[0], f1 = p[1];
    o.x = pk2(f0.x, f0.y); o.y = pk2(f0.z, f0.w);
    o.z = pk2(f1.x, f1.y); o.w = pk2(f1.z, f1.w);
  } else {
    o = make_uint4(0u, 0u, 0u, 0u);
  }
  size_t off = (size_t)((b * NLT + t) * NKK + kk) * TILE + (size_t)r * 128 + ((gn ^ (r & 7)) << 4);
  *(uint4*)(Xt + off) = o;
}

// ---- fused dual-GEMM + online softmax; 512 thr = 8 waves (2M x 4N), 256x256 tile
// Block id packing (L2 locality): id = (yblk*NSPL + split)*8 + bb.
//   XCD = id&7 = bb  -> this XCD's X slice (2.6 MB) stays L2-resident.
//   Within an XCD, consecutive n = yblk*NSPL+split -> concurrent window spans
//   ~6 yblks (G working set ~1.6 MB) instead of ~32 (8 MB, thrash).
template<int LSPL, int NSPL, bool PARTIAL>
__global__ __launch_bounds__(512, 2) void fused_kernel(
    const char* __restrict__ Gt, const char* __restrict__ Xt,
    const float* __restrict__ bias, float* __restrict__ out,
    float* __restrict__ PM, float* __restrict__ PD, float* __restrict__ PN)
{
  __shared__ uint4 AsRaw[2 * TILE / 16];   // 64 KB
  __shared__ uint4 BsRaw[2 * TILE / 16];   // 64 KB
  char* AsC = (char*)AsRaw;
  char* BsC = (char*)BsRaw;

  const int tid  = threadIdx.x;
  const int lane = tid & 63;
  const int w    = tid >> 6;        // 0..7
  const int wr   = w >> 2;          // 0..1  M-half
  const int wc   = w & 3;           // 0..3  N-quarter
  const int cl   = lane & 15, g = lane >> 4;

  const int id    = blockIdx.x;
  const int bb    = id & 7;         // batch, XCD-pinned by round-robin dispatch
  const int n     = id >> 3;
  const int yblk  = n / NSPL;
  const int split = n - yblk * NSPL;
  const int tbase = split * LSPL;

  const char* GA = Gt + (size_t)yblk * NKK * TILE;
  const char* XB = Xt + ((size_t)bb * NLT + tbase) * NKK * TILE;

  f4v acc[8][4];
  float runM[8][2], runD[8][2], runN[8][2];
  #pragma unroll
  for (int mi = 0; mi < 8; ++mi)
    #pragma unroll
    for (int p = 0; p < 2; ++p) { runM[mi][p] = -1e30f; runD[mi][p] = 0.f; runN[mi][p] = 0.f; }

  const int soff = w * 1024 + lane * 16;
  auto stageAll = [&](int buf, int u) {
    const char* ga = GA + (size_t)(u & 7) * TILE;
    const char* gb = XB + (size_t)u * TILE;         // X layout [t][kk] contiguous
    #pragma unroll
    for (int i = 0; i < 4; ++i) {
      async_copy16(ga + i * 8192 + soff, AsC + buf * TILE + i * 8192 + w * 1024);
      async_copy16(gb + i * 8192 + soff, BsC + buf * TILE + i * 8192 + w * 1024);
    }
  };

  // prologue
  stageAll(0, 0);
  asm volatile("s_waitcnt vmcnt(0)" ::: "memory");
  __builtin_amdgcn_s_barrier();
  asm volatile("" ::: "memory");

  for (int t = 0; t < LSPL; ++t) {
    #pragma unroll
    for (int mi = 0; mi < 8; ++mi)
      #pragma unroll
      for (int ni = 0; ni < 4; ++ni)
        #pragma unroll
        for (int q = 0; q < 4; ++q) acc[mi][ni][q] = 0.f;

    for (int kk = 0; kk < NKK; ++kk) {
      const int u = t * NKK + kk;
      const int cur = u & 1;
      const char* A = AsC + cur * TILE;
      const char* B = BsC + cur * TILE;

      // issue next K-step staging first: max latency cover before boundary drain
      if (u + 1 < LSPL * NKK) stageAll(cur ^ 1, u + 1);

      s8v bv[4][2];
      #pragma unroll
      for (int ni = 0; ni < 4; ++ni)
        #pragma unroll
        for (int kf = 0; kf < 2; ++kf) {
          int r = wc * 64 + ni * 16 + cl;
          bv[ni][kf] = *(const s8v*)(B + r * 128 + ((kf * 64 + g * 16) ^ ((r & 7) << 4)));
        }

      #pragma unroll
      for (int ph = 0; ph < 4; ++ph) {
        s8v af[2][2];
        #pragma unroll
        for (int j = 0; j < 2; ++j)
          #pragma unroll
          for (int kf = 0; kf < 2; ++kf) {
            int r = wr * 128 + (ph * 2 + j) * 16 + cl;
            af[j][kf] = *(const s8v*)(A + r * 128 + ((kf * 64 + g * 16) ^ ((r & 7) << 4)));
          }
        __builtin_amdgcn_s_barrier();             // align waves: reads done, MFMA next
        __builtin_amdgcn_s_setprio(1);
        #pragma unroll
        for (int kf = 0; kf < 2; ++kf)
          #pragma unroll
          for (int j = 0; j < 2; ++j)
            #pragma unroll
            for (int ni = 0; ni < 4; ++ni)
              acc[ph * 2 + j][ni] = __builtin_amdgcn_mfma_f32_16x16x32_bf16(
                  af[j][kf], bv[ni][kf], acc[ph * 2 + j][ni], 0, 0, 0);
        __builtin_amdgcn_s_setprio(0);
        if (ph < 3) __builtin_amdgcn_s_barrier();
      }

      // ---- per-l-tile online-softmax (register + 16-lane shuffles), hides vmcnt drain
      if (kk == NKK - 1) {
        const int lbase = (tbase + t) * BN + wc * 64 + cl;
        #pragma unroll
        for (int mi = 0; mi < 8; ++mi) {
          #pragma unroll
          for (int p = 0; p < 2; ++p) {
            float sv[4], tv[4], mloc = -1e30f;
            #pragma unroll
            for (int ni = 0; ni < 4; ++ni) {
              bool valid = (lbase + ni * 16) < NL;
              sv[ni] = valid ? acc[mi][ni][2 * p] : -1e30f;
              tv[ni] = acc[mi][ni][2 * p + 1];
              mloc = fmaxf(mloc, sv[ni]);
            }
            #pragma unroll
            for (int off = 1; off < 16; off <<= 1) mloc = fmaxf(mloc, __shfl_xor(mloc, off));
            float newM = fmaxf(runM[mi][p], mloc);
            float se = 0.f, ste = 0.f;
            #pragma unroll
            for (int ni = 0; ni < 4; ++ni) {
              float e = __expf(sv[ni] - newM);
              se += e; ste += e * tv[ni];
            }
            #pragma unroll
            for (int off = 1; off < 16; off <<= 1) { se += __shfl_xor(se, off); ste += __shfl_xor(ste, off); }
            float sc = __expf(runM[mi][p] - newM);
            runD[mi][p] = runD[mi][p] * sc + se;
            runN[mi][p] = runN[mi][p] * sc + ste;
            runM[mi][p] = newM;
          }
        }
      }

      // K-step boundary: drain staging, switch buffers
      asm volatile("s_waitcnt vmcnt(0)" ::: "memory");
      __builtin_amdgcn_s_barrier();
      asm volatile("" ::: "memory");
    }
  }

  // ---- 4-way wc merge via LDS, then write partials / output
  __syncthreads();
  float* sm = (float*)AsRaw;     // 128 labels x 4 wc x 3 floats = 6 KB
  if (cl == 0) {
    #pragma unroll
    for (int mi = 0; mi < 8; ++mi)
      #pragma unroll
      for (int p = 0; p < 2; ++p) {
        int lab = wr * 64 + mi * 8 + 2 * g + p;   // 0..127
        float* s3 = sm + (lab * 4 + wc) * 3;
        s3[0] = runM[mi][p]; s3[1] = runD[mi][p]; s3[2] = runN[mi][p];
      }
  }
  __syncthreads();
  if (tid < 128) {
    float M = -1e30f, D = 0.f, N = 0.f;
    #pragma unroll
    for (int q = 0; q < 4; ++q) {
      const float* s3 = sm + (tid * 4 + q) * 3;
      float M1 = s3[0], D1 = s3[1], N1 = s3[2];
      float Mn = fmaxf(M, M1);
      float e0 = __expf(M - Mn), e1 = __expf(M1 - Mn);
      D = D * e0 + D1 * e1;
      N = N * e0 + N1 * e1;
      M = Mn;
    }
    int y = yblk * 128 + tid;
    if constexpr (PARTIAL) {
      size_t o = ((size_t)split * NB + bb) * YPAD + y;
      PM[o] = M; PD[o] = D; PN[o] = N;
    } else {
      if (y < NY) out[(size_t)bb * NY + y] = N / D + bias[y];
    }
  }
}

// ---- merge SPLIT partials + bias -> out
__global__ void merge_kernel(const float* __restrict__ PM, const float* __restrict__ PD,
                             const float* __restrict__ PN, const float* __restrict__ bias,
                             float* __restrict__ out) {
  int idx = blockIdx.x * 256 + threadIdx.x;      // NB*YPAD
  int b = idx / YPAD, y = idx - b * YPAD;
  if (y >= NY) return;
  float M = -1e30f, D = 0.f, N = 0.f;
  #pragma unroll
  for (int s = 0; s < SPLIT; ++s) {
    size_t o = ((size_t)s * NB + b) * YPAD + y;
    float M1 = PM[o], D1 = PD[o], N1 = PN[o];
    float Mn = fmaxf(M, M1);
    float e0 = __expf(M - Mn), e1 = __expf(M1 - Mn);
    D = D * e0 + D1 * e1;
    N = N * e0 + N1 * e1;
    M = Mn;
  }
  out[(size_t)b * NY + y] = N / D + bias[y];
}

extern "C" void kernel_launch(void* const* d_in, const int* in_sizes, int n_in,
                              void* d_out, int out_size, void* d_ws, size_t ws_size,
                              hipStream_t stream) {
  const float* xf   = (const float*)d_in[0];
  const float* Uf   = (const float*)d_in[1];
  const float* Wf   = (const float*)d_in[2];
  const float* bias = (const float*)d_in[3];
  float* out = (float*)d_out;

  char* Gt = (char*)d_ws;
  char* Xt = Gt + GT_BYTES;
  float* PM = (float*)(Xt + XT_BYTES);
  float* PD = PM + P_ELEMS;
  float* PN = PD + P_ELEMS;

  cvt_g_kernel<<<4480, 256, 0, stream>>>(Uf, Wf, Gt);
  cvt_x_kernel<<<5120, 256, 0, stream>>>(xf, Xt);

  const size_t need_main = GT_BYTES + XT_BYTES + 3 * P_BYTES;   // ~43.6 MB
  if (ws_size >= need_main) {
    fused_kernel<LSPL_MAIN, SPLIT, true><<<NYB * NB * SPLIT, 512, 0, stream>>>(
        Gt, Xt, bias, out, PM, PD, PN);
    merge_kernel<<<NB * YPAD / 256, 256, 0, stream>>>(PM, PD, PN, bias, out);
  } else {
    fused_kernel<NLT, 1, false><<<NYB * NB, 512, 0, stream>>>(
        Gt, Xt, bias, out, PM, PD, PN);
  }
}

// Round 6
// 501.090 us; speedup vs baseline: 5.1494x; 1.0093x over previous
//
#include <hip/hip_runtime.h>
#include <hip/hip_bf16.h>

// Problem constants
#define NB 8
#define NL 2500
#define ND 512
#define NY 8921

// Tiling
#define BM 256             // G rows per block (128 labels, U/W interleaved)
#define BN 256             // l-tile
#define BK 32              // k-slice
#define NKS 16             // ND/BK slices per l-tile
#define LPAD 2560          // 10 * 256
#define NLT 10             // LPAD/BN
#define NYB 70             // ceil(NY/128)
#define YPAD 8960          // NYB*128

#define SPLIT 5            // l-range splits (2 l-tiles per block)
#define LSPL_MAIN 2

#define TILE 16384         // 256 rows x 32 bf16 (64B/row), row-pair swizzled image
#define GT_BYTES ((size_t)NYB * NKS * TILE)              // 18,350,080
#define XT_BYTES ((size_t)NB * NLT * NKS * TILE)         // 20,971,520
#define P_ELEMS  ((size_t)SPLIT * NB * YPAD)             // 358,400
#define P_BYTES  (P_ELEMS * 4)

typedef short s8v __attribute__((ext_vector_type(8)));
typedef float f4v __attribute__((ext_vector_type(4)));

__device__ __forceinline__ unsigned short f2bf(float f) {
  unsigned int u = __float_as_uint(f);
  return (unsigned short)((u + 0x7FFFu + ((u >> 16) & 1u)) >> 16);
}
__device__ __forceinline__ unsigned int pk2(float a, float b) {
  return (unsigned int)f2bf(a) | ((unsigned int)f2bf(b) << 16);
}
__device__ __forceinline__ void async_copy16(const char* g, char* l) {
  __builtin_amdgcn_global_load_lds(
      (const __attribute__((address_space(1))) void*)g,
      (__attribute__((address_space(3))) void*)l, 16, 0, 0);
}

// Swizzled tile byte offset for (row r in [0,256), 16B-granule gn in [0,4)):
// row-pair rp=r>>1 owns a 128B line; within-line offset = ((r&1)*64 + gn*16) ^ ((rp&7)<<4)
__device__ __forceinline__ int tile_off(int r, int gn) {
  int rp = r >> 1;
  return rp * 128 + ((((r & 1) << 6) | (gn << 4)) ^ ((rp & 7) << 4));
}

// ---- G: interleave U/W rows (row 2y=U[y], 2y+1=W[y]) -> bf16 swizzled slice-tiles
// layout [yblk 70][ks 16][16KB tile]
__global__ void cvt_g_kernel(const float* __restrict__ U, const float* __restrict__ W,
                             char* __restrict__ Gt) {
  int c = blockIdx.x * 256 + threadIdx.x;      // one 16B granule
  int g10 = c & 1023;                          // granule within tile
  int tile = c >> 10;                          // yblk*16 + ks
  int ks = tile & 15, yblk = tile >> 4;
  int r = g10 >> 2, gn = g10 & 3;
  int rg = yblk * 256 + r;                     // global G row
  int y = rg >> 1;
  uint4 o;
  if (y < NY) {
    const float* src = (rg & 1) ? W : U;
    const float4* p = (const float4*)(src + (size_t)y * ND + ks * BK + gn * 8);
    float4 f0 = p[0], f1 = p[1];
    o.x = pk2(f0.x, f0.y); o.y = pk2(f0.z, f0.w);
    o.z = pk2(f1.x, f1.y); o.w = pk2(f1.z, f1.w);
  } else {
    o = make_uint4(0u, 0u, 0u, 0u);
  }
  *(uint4*)(Gt + (size_t)tile * TILE + tile_off(r, gn)) = o;
}

// ---- x -> bf16 swizzled slice-tiles: [b 8][t 10][ks 16][16KB], zero-pad l>=2500
__global__ void cvt_x_kernel(const float* __restrict__ x, char* __restrict__ Xt) {
  int c = blockIdx.x * 256 + threadIdx.x;
  int g10 = c & 1023;
  int tile = c >> 10;                          // (b*10+t)*16 + ks
  int ks = tile & 15, rest = tile >> 4;
  int t = rest % NLT, b = rest / NLT;
  int r = g10 >> 2, gn = g10 & 3;
  int l = t * 256 + r;
  uint4 o;
  if (l < NL) {
    const float4* p = (const float4*)(x + ((size_t)b * NL + l) * ND + ks * BK + gn * 8);
    float4 f0 = p[0], f1 = p[1];
    o.x = pk2(f0.x, f0.y); o.y = pk2(f0.z, f0.w);
    o.z = pk2(f1.x, f1.y); o.w = pk2(f1.z, f1.w);
  } else {
    o = make_uint4(0u, 0u, 0u, 0u);
  }
  *(uint4*)(Xt + (size_t)tile * TILE + tile_off(r, gn)) = o;
}

// ---- fused dual-GEMM + online softmax; 512 thr = 8 waves (2M x 4N), 256x256 tile
// 4-deep LDS ring of BK=32 slices; counted vmcnt(8) at slice boundaries (T4):
// slices u+2, u+3 stay in flight across the barrier — never drain to 0 mid-loop.
template<int LSPL, int NSPL, bool PARTIAL>
__global__ __launch_bounds__(512, 2) void fused_kernel(
    const char* __restrict__ Gt, const char* __restrict__ Xt,
    const float* __restrict__ bias, float* __restrict__ out,
    float* __restrict__ PM, float* __restrict__ PD, float* __restrict__ PN)
{
  __shared__ uint4 AsRaw[4 * 1024];    // 4 x 16KB ring slots (A)
  __shared__ uint4 BsRaw[4 * 1024];    // 4 x 16KB ring slots (B)
  char* AsC = (char*)AsRaw;
  char* BsC = (char*)BsRaw;

  constexpr int NS = LSPL * NKS;       // total k-slices per block

  const int tid  = threadIdx.x;
  const int lane = tid & 63;
  const int w    = tid >> 6;           // 0..7
  const int wr   = w >> 2;             // 0..1  M-half
  const int wc   = w & 3;              // 0..3  N-quarter
  const int cl   = lane & 15, g = lane >> 4;

  const int id    = blockIdx.x;
  const int bb    = id & 7;            // batch, XCD-pinned
  const int n     = id >> 3;
  const int yblk  = n / NSPL;
  const int split = n - yblk * NSPL;
  const int tbase = split * LSPL;

  const char* GA = Gt + (size_t)yblk * NKS * TILE;
  const char* XB = Xt + ((size_t)bb * NLT + tbase) * NKS * TILE;

  f4v acc[8][4];
  float runM[8][2], runD[8][2], runN[8][2];
  #pragma unroll
  for (int mi = 0; mi < 8; ++mi)
    #pragma unroll
    for (int p = 0; p < 2; ++p) { runM[mi][p] = -1e30f; runD[mi][p] = 0.f; runN[mi][p] = 0.f; }

  const int soff = tid * 16;           // per-lane global offset within 8KB half-tile
  const int woff = (tid >> 6) * 1024;  // per-WAVE LDS segment (HW: lds dst = wave-uniform base + lane*16)
  auto stageA = [&](int s) {           // 2 loads: A slice s -> slot s&3
    const char* ga = GA + (size_t)(s & 15) * TILE;
    char* la = AsC + (s & 3) * TILE + woff;
    async_copy16(ga + soff, la);
    async_copy16(ga + 8192 + soff, la + 8192);
  };
  auto stageB = [&](int s) {           // 2 loads: B slice s -> slot s&3
    const char* gb = XB + (size_t)s * TILE;
    char* lb = BsC + (s & 3) * TILE + woff;
    async_copy16(gb + soff, lb);
    async_copy16(gb + 8192 + soff, lb + 8192);
  };

  // prologue: prime 3 slices (12 loads in flight), retire slice 0 only
  stageA(0); stageB(0);
  stageA(1); stageB(1);
  stageA(2); stageB(2);
  asm volatile("s_waitcnt vmcnt(8)" ::: "memory");
  __builtin_amdgcn_s_barrier();

  for (int t = 0; t < LSPL; ++t) {
    #pragma unroll
    for (int mi = 0; mi < 8; ++mi)
      #pragma unroll
      for (int ni = 0; ni < 4; ++ni)
        #pragma unroll
        for (int q = 0; q < 4; ++q) acc[mi][ni][q] = 0.f;

    for (int ks = 0; ks < NKS; ++ks) {
      const int u = t * NKS + ks;
      const char* A = AsC + (u & 3) * TILE;
      const char* B = BsC + (u & 3) * TILE;
      const bool hn = (u + 3) < NS;

      if (hn) stageA(u + 3);           // into slot (u-1)&3, freed at last barrier

      // phase 0: B frags + A frags (mi 0..3)
      s8v bv[4], af[4];
      #pragma unroll
      for (int ni = 0; ni < 4; ++ni) {
        int r = wc * 64 + ni * 16 + cl;
        bv[ni] = *(const s8v*)(B + tile_off(r, g));
      }
      #pragma unroll
      for (int j = 0; j < 4; ++j) {
        int r = wr * 128 + j * 16 + cl;
        af[j] = *(const s8v*)(A + tile_off(r, g));
      }
      __builtin_amdgcn_s_barrier();    // pacing: align MFMA clusters
      __builtin_amdgcn_s_setprio(1);
      #pragma unroll
      for (int j = 0; j < 4; ++j)
        #pragma unroll
        for (int ni = 0; ni < 4; ++ni)
          acc[j][ni] = __builtin_amdgcn_mfma_f32_16x16x32_bf16(af[j], bv[ni], acc[j][ni], 0, 0, 0);
      __builtin_amdgcn_s_setprio(0);

      if (hn) stageB(u + 3);

      // phase 1: A frags (mi 4..7)
      #pragma unroll
      for (int j = 0; j < 4; ++j) {
        int r = wr * 128 + (4 + j) * 16 + cl;
        af[j] = *(const s8v*)(A + tile_off(r, g));
      }
      __builtin_amdgcn_s_barrier();
      __builtin_amdgcn_s_setprio(1);
      #pragma unroll
      for (int j = 0; j < 4; ++j)
        #pragma unroll
        for (int ni = 0; ni < 4; ++ni)
          acc[4 + j][ni] = __builtin_amdgcn_mfma_f32_16x16x32_bf16(af[j], bv[ni], acc[4 + j][ni], 0, 0, 0);
      __builtin_amdgcn_s_setprio(0);

      // ---- per-l-tile online-softmax (registers + 16-lane shuffles), covers drain
      if (ks == NKS - 1) {
        const int lbase = (tbase + t) * BN + wc * 64 + cl;
        #pragma unroll
        for (int mi = 0; mi < 8; ++mi) {
          #pragma unroll
          for (int p = 0; p < 2; ++p) {
            float sv[4], tv[4], mloc = -1e30f;
            #pragma unroll
            for (int ni = 0; ni < 4; ++ni) {
              bool valid = (lbase + ni * 16) < NL;
              sv[ni] = valid ? acc[mi][ni][2 * p] : -1e30f;
              tv[ni] = acc[mi][ni][2 * p + 1];
              mloc = fmaxf(mloc, sv[ni]);
            }
            #pragma unroll
            for (int off = 1; off < 16; off <<= 1) mloc = fmaxf(mloc, __shfl_xor(mloc, off));
            float newM = fmaxf(runM[mi][p], mloc);
            float se = 0.f, ste = 0.f;
            #pragma unroll
            for (int ni = 0; ni < 4; ++ni) {
              float e = __expf(sv[ni] - newM);
              se += e; ste += e * tv[ni];
            }
            #pragma unroll
            for (int off = 1; off < 16; off <<= 1) { se += __shfl_xor(se, off); ste += __shfl_xor(ste, off); }
            float sc = __expf(runM[mi][p] - newM);
            runD[mi][p] = runD[mi][p] * sc + se;
            runN[mi][p] = runN[mi][p] * sc + ste;
            runM[mi][p] = newM;
          }
        }
      }

      // slice boundary: counted wait (retire u+1's 4 loads; u+2,u+3 stay in flight)
      if (u < NS - 3) {
        asm volatile("s_waitcnt vmcnt(8)" ::: "memory");
      } else {
        asm volatile("s_waitcnt vmcnt(0)" ::: "memory");
      }
      __builtin_amdgcn_s_barrier();
    }
  }

  // ---- 4-way wc merge via LDS, then write partials / output
  __syncthreads();
  float* sm = (float*)AsRaw;     // 128 labels x 4 wc x 3 floats = 6 KB
  if (cl == 0) {
    #pragma unroll
    for (int mi = 0; mi < 8; ++mi)
      #pragma unroll
      for (int p = 0; p < 2; ++p) {
        int lab = wr * 64 + mi * 8 + 2 * g + p;   // 0..127
        float* s3 = sm + (lab * 4 + wc) * 3;
        s3[0] = runM[mi][p]; s3[1] = runD[mi][p]; s3[2] = runN[mi][p];
      }
  }
  __syncthreads();
  if (tid < 128) {
    float M = -1e30f, D = 0.f, N = 0.f;
    #pragma unroll
    for (int q = 0; q < 4; ++q) {
      const float* s3 = sm + (tid * 4 + q) * 3;
      float M1 = s3[0], D1 = s3[1], N1 = s3[2];
      float Mn = fmaxf(M, M1);
      float e0 = __expf(M - Mn), e1 = __expf(M1 - Mn);
      D = D * e0 + D1 * e1;
      N = N * e0 + N1 * e1;
      M = Mn;
    }
    int y = yblk * 128 + tid;
    if constexpr (PARTIAL) {
      size_t o = ((size_t)split * NB + bb) * YPAD + y;
      PM[o] = M; PD[o] = D; PN[o] = N;
    } else {
      if (y < NY) out[(size_t)bb * NY + y] = N / D + bias[y];
    }
  }
}

// ---- merge SPLIT partials + bias -> out
__global__ void merge_kernel(const float* __restrict__ PM, const float* __restrict__ PD,
                             const float* __restrict__ PN, const float* __restrict__ bias,
                             float* __restrict__ out) {
  int idx = blockIdx.x * 256 + threadIdx.x;      // NB*YPAD
  int b = idx / YPAD, y = idx - b * YPAD;
  if (y >= NY) return;
  float M = -1e30f, D = 0.f, N = 0.f;
  #pragma unroll
  for (int s = 0; s < SPLIT; ++s) {
    size_t o = ((size_t)s * NB + b) * YPAD + y;
    float M1 = PM[o], D1 = PD[o], N1 = PN[o];
    float Mn = fmaxf(M, M1);
    float e0 = __expf(M - Mn), e1 = __expf(M1 - Mn);
    D = D * e0 + D1 * e1;
    N = N * e0 + N1 * e1;
    M = Mn;
  }
  out[(size_t)b * NY + y] = N / D + bias[y];
}

extern "C" void kernel_launch(void* const* d_in, const int* in_sizes, int n_in,
                              void* d_out, int out_size, void* d_ws, size_t ws_size,
                              hipStream_t stream) {
  const float* xf   = (const float*)d_in[0];
  const float* Uf   = (const float*)d_in[1];
  const float* Wf   = (const float*)d_in[2];
  const float* bias = (const float*)d_in[3];
  float* out = (float*)d_out;

  char* Gt = (char*)d_ws;
  char* Xt = Gt + GT_BYTES;
  float* PM = (float*)(Xt + XT_BYTES);
  float* PD = PM + P_ELEMS;
  float* PN = PD + P_ELEMS;

  // G granules: 17920 rows * 64 = 1,146,880 / 256 = 4480 blocks
  cvt_g_kernel<<<4480, 256, 0, stream>>>(Uf, Wf, Gt);
  // x granules: 8*2560 rows * 64 = 1,310,720 / 256 = 5120 blocks
  cvt_x_kernel<<<5120, 256, 0, stream>>>(xf, Xt);

  const size_t need_main = GT_BYTES + XT_BYTES + 3 * P_BYTES;   // ~43.6 MB
  if (ws_size >= need_main) {
    fused_kernel<LSPL_MAIN, SPLIT, true><<<NYB * NB * SPLIT, 512, 0, stream>>>(
        Gt, Xt, bias, out, PM, PD, PN);
    merge_kernel<<<NB * YPAD / 256, 256, 0, stream>>>(PM, PD, PN, bias, out);
  } else {
    fused_kernel<NLT, 1, false><<<NYB * NB, 512, 0, stream>>>(
        Gt, Xt, bias, out, PM, PD, PN);
  }
}